// Round 4
// baseline (338.739 us; speedup 1.0000x reference)
//
#include <hip/hip_runtime.h>
#include <hip/hip_bf16.h>

#define N_NODES 50000
#define N_EDGES 800000
#define CAP 48                       // max deg ~45 for Poisson(16) over 50K (48=8sigma)
#define NODE_BLOCKS 6250             // 8 nodes/block, one pass, no batch loop
#define BUCKET_BLOCKS (N_EDGES/256)  // 3125 exact, 1 edge/thread

__device__ __forceinline__ unsigned short f2bf(float f) {
    union { float f; unsigned u; } t; t.f = f;
    unsigned r = t.u + 0x7FFF + ((t.u >> 16) & 1);   // RNE
    return (unsigned short)(r >> 16);
}

// ---------------------------------------------------------------------------
// Fused prep, role-split (roles run CONCURRENTLY via grid co-residency —
// the 3-kernel split measured +45 us from serializing them):
//  node role (blocks 0..6249): lin1 + self-connection, 8 nodes/block.
//    v4: ZERO LDS, zero barriers. x read as broadcast float4 global loads
//    (uniform addr per 32-lane group -> one L1 line access each; row is
//    L1-resident for the group's reuse). W1 columns in 64 VGPRs. Wsc from
//    global (32 KB, L1-resident, coalesced 128B/group). 6250 blocks (was
//    1250 + serial 5-batch loop) -> 5x block parallelism for latency hiding.
//    Rationale: prior LDS-broadcast version issued 96 LDS instrs/lane/node
//    on one LDS pipe/CU at ~5 blocks/CU — LDS-issue bound, underoccupied.
//  bucket role: reverse-CSR build, 1 edge/thread. counts compact (the
//    64B-line padding measured neutral; line contention was NOT the wall).
// ---------------------------------------------------------------------------
__global__ __launch_bounds__(256) void prep_kernel(
    const float* __restrict__ x, const float* __restrict__ attr,
    const float* __restrict__ W1s, const float* __restrict__ W1v,
    const float* __restrict__ Wscs, const float* __restrict__ Wscv,
    const int* __restrict__ eidx,
    int* __restrict__ counts, int* __restrict__ bucket,
    unsigned short* __restrict__ ysvh, float* __restrict__ out)
{
    const int tid = threadIdx.x;

    if (blockIdx.x < NODE_BLOCKS) {
        // ---------------- node role ----------------
        const int nl = tid >> 5;
        const int w  = tid & 31;
        const int node = blockIdx.x * 8 + nl;

        // W1 columns (column w, all u) in registers — loaded once, coalesced
        float w1s[32], w1v[32];
        #pragma unroll
        for (int u = 0; u < 32; ++u) {
            w1s[u] = W1s[u*32 + w];
            w1v[u] = W1v[u*32 + w];
        }

        const float* at = attr + (long)node * 4;
        int sp = 0;
        if (at[1] > 0.5f) sp = 1;
        if (at[2] > 0.5f) sp = 2;
        if (at[3] > 0.5f) sp = 3;

        const float4* xr   = (const float4*)(x + (long)node * 128);
        const float*  gscs = Wscs + sp * 32 + w;   // L1-resident table
        const float*  gscv = Wscv + sp * 32 + w;

        const float l1n = 0.17677669529663687f;   // 1/sqrt(32)
        const float scn = 0.08838834764831843f;   // 1/sqrt(128)

        float ys = 0.f, yv0 = 0.f, yv1 = 0.f, yv2 = 0.f;
        float ss = 0.f, sv0 = 0.f, sv1 = 0.f, sv2 = 0.f;
        #pragma unroll
        for (int u4 = 0; u4 < 8; ++u4) {
            // broadcast float4 loads (group-uniform addr -> 1 L1 line each)
            const float4 xs4 = xr[u4];
            const float4 q0  = xr[8 + u4*3 + 0];
            const float4 q1  = xr[8 + u4*3 + 1];
            const float4 q2  = xr[8 + u4*3 + 2];
            const float xsv[4]  = {xs4.x, xs4.y, xs4.z, xs4.w};
            const float xvv[12] = {q0.x,q0.y,q0.z,q0.w,
                                   q1.x,q1.y,q1.z,q1.w,
                                   q2.x,q2.y,q2.z,q2.w};
            #pragma unroll
            for (int j = 0; j < 4; ++j) {
                const int u = u4*4 + j;
                const float wss = gscs[u*128];   // coalesced 128B / group
                const float wsv = gscv[u*128];
                ys  += xsv[j] * w1s[u];
                yv0 += xvv[3*j+0] * w1v[u];
                yv1 += xvv[3*j+1] * w1v[u];
                yv2 += xvv[3*j+2] * w1v[u];
                ss  += xsv[j] * wss;
                sv0 += xvv[3*j+0] * wsv;
                sv1 += xvv[3*j+1] * wsv;
                sv2 += xvv[3*j+2] * wsv;
            }
        }

        uint2 pk;
        pk.x = (unsigned)f2bf(ys  * l1n) | ((unsigned)f2bf(yv0 * l1n) << 16);
        pk.y = (unsigned)f2bf(yv1 * l1n) | ((unsigned)f2bf(yv2 * l1n) << 16);
        *(uint2*)(ysvh + (long)node * 128 + w * 4) = pk;

        float* op = out + (long)node * 128;
        op[w] = ss * scn;
        op[32 + 3*w + 0] = sv0 * scn;
        op[32 + 3*w + 1] = sv1 * scn;
        op[32 + 3*w + 2] = sv2 * scn;
    } else {
        // ---------------- bucket role (1 edge/thread) ----------------
        const int e = (blockIdx.x - NODE_BLOCKS) * 256 + tid;
        const int dst = eidx[N_EDGES + e];
        const int slot = atomicAdd(&counts[dst], 1);
        if (slot < CAP) bucket[(long)dst * CAP + slot] = e;
    }
}

// ---------------------------------------------------------------------------
// Aggregation: 8 nodes / 256-thread block, 32 lanes per node-group. FiLM
// computed in-kernel lane-parallel (prologue) into LDS; loop body: broadcast
// ds_read of {h',attr} + prefetched ysv gathers ONLY. 4 edges/iter with the
// next 4 gathers in flight (depth-8 measured slower). Dummy slots gather
// node 0 (one hot L1 line) instead of a random src.
// ---------------------------------------------------------------------------
__global__ __launch_bounds__(256) void agg_kernel(
    const float* __restrict__ ee, const float* __restrict__ eattr,
    const int* __restrict__ eidx,
    const float* __restrict__ fcw1, const float* __restrict__ fcw2,
    const float* __restrict__ W2s, const float* __restrict__ W2v,
    const unsigned short* __restrict__ ysvh,
    const int* __restrict__ counts, const int* __restrict__ bucket,
    float* __restrict__ out)
{
    __shared__ float hrec[8][32 * 12];  // 12 KB: per group, per slot {h'[8], attr[4]}
    __shared__ float mid[8][256];       // 8 KB

    const int tid = threadIdx.x;
    const int nl = tid >> 5;
    const int u  = tid & 31;
    const int node = blockIdx.x * 8 + nl;
    const float inv_sqrt8 = 0.35355339059327373f;

    // fc2 fragment: f2r[j][q] = fcw2[j*128 + q*32 + u]
    float f2r[8][4];
    #pragma unroll
    for (int j = 0; j < 8; ++j) {
        f2r[j][0] = fcw2[j*128 + u];
        f2r[j][1] = fcw2[j*128 + 32 + u];
        f2r[j][2] = fcw2[j*128 + 64 + u];
        f2r[j][3] = fcw2[j*128 + 96 + u];
    }

    const int cnt = min(counts[node], CAP);
    int e0 = bucket[(long)node * CAP + u];   // u<32<CAP, safe
    const bool dummy = (u >= cnt);
    if (dummy) e0 = 0;
    const int s0 = dummy ? 0 : eidx[e0];   // dummy gathers hit node 0 (hot line)

    // ---- prologue: lane u computes FiLM h' for its own slot's edge ----
    {
        const float4 ea = ((const float4*)(ee + (long)e0 * 8))[0];
        const float4 eb = ((const float4*)(ee + (long)e0 * 8))[1];
        const float4 at = ((const float4*)eattr)[e0];
        const float eev[8] = {ea.x, ea.y, ea.z, ea.w, eb.x, eb.y, eb.z, eb.w};
        float* hr = hrec[nl] + u * 12;
        float h[8];
        #pragma unroll
        for (int j = 0; j < 8; ++j) {
            float pre = 0.f;
            #pragma unroll
            for (int b = 0; b < 8; ++b) pre += eev[b] * fcw1[b*8 + j];
            pre *= inv_sqrt8;
            const float s = pre / (1.f + __expf(-pre)) * inv_sqrt8;
            h[j] = dummy ? 0.f : s;     // h'=0 kills every term of a dummy slot
        }
        ((float4*)hr)[0] = make_float4(h[0], h[1], h[2], h[3]);
        ((float4*)hr)[1] = make_float4(h[4], h[5], h[6], h[7]);
        ((float4*)hr)[2] = at;
        // no barrier: written and read by the same 32-lane group (wave-sync)
    }

    float msa = 0.f, msb = 0.f;
    float va0 = 0.f, va1 = 0.f, va2 = 0.f;
    float vb0 = 0.f, vb1 = 0.f, vb2 = 0.f;

    #define ACCUM(HA, HB, AT, Y)                                             \
    {                                                                        \
        const float es = __uint_as_float((Y).x << 16);                       \
        const float ex = __uint_as_float((Y).x & 0xffff0000u);               \
        const float ey = __uint_as_float((Y).y << 16);                       \
        const float ez = __uint_as_float((Y).y & 0xffff0000u);               \
        const float hh[8] = {HA.x,HA.y,HA.z,HA.w,HB.x,HB.y,HB.z,HB.w};       \
        float w00=0.f, w01=0.f, w10=0.f, w11=0.f;                            \
        _Pragma("unroll")                                                    \
        for (int j = 0; j < 8; ++j) {                                        \
            w00 += hh[j]*f2r[j][0]; w01 += hh[j]*f2r[j][1];                  \
            w10 += hh[j]*f2r[j][2]; w11 += hh[j]*f2r[j][3];                  \
        }                                                                    \
        const float a0 = AT.x, a1x = AT.y, a1y = AT.z, a1z = AT.w;           \
        msa += w00 * es * a0;                                                \
        msb += w11 * (ex*a1x + ey*a1y + ez*a1z);                             \
        const float t = w01 * es;                                            \
        va0 += t*a1x; va1 += t*a1y; va2 += t*a1z;                            \
        const float s = w10 * a0;                                            \
        vb0 += s*ex; vb1 += s*ey; vb2 += s*ez;                               \
    }

    #define GATHER(SLOT) \
        (*(const uint2*)(ysvh + (long)__shfl(s0, (SLOT), 32) * 128 + u * 4))

    // ---- main loop: 4 edges/iter, next 4 gathers in flight ----
    const int c0 = min(cnt, 32);
    {
        uint2 y0 = GATHER(0), y1 = GATHER(1), y2 = GATHER(2), y3 = GATHER(3);
        for (int k = 0; k < c0; k += 4) {
            const int kn = (k + 4) & 31;            // wrap: dummy-safe
            const uint2 n0 = GATHER(kn);
            const uint2 n1 = GATHER(kn + 1);
            const uint2 n2 = GATHER(kn + 2);
            const uint2 n3 = GATHER(kn + 3);
            const float4* h0p = (const float4*)(hrec[nl] + (k + 0) * 12);
            const float4* h1p = (const float4*)(hrec[nl] + (k + 1) * 12);
            const float4* h2p = (const float4*)(hrec[nl] + (k + 2) * 12);
            const float4* h3p = (const float4*)(hrec[nl] + (k + 3) * 12);
            const float4 A0 = h0p[0], B0 = h0p[1], T0 = h0p[2];
            const float4 A1 = h1p[0], B1 = h1p[1], T1 = h1p[2];
            const float4 A2 = h2p[0], B2 = h2p[1], T2 = h2p[2];
            const float4 A3 = h3p[0], B3 = h3p[1], T3 = h3p[2];
            ACCUM(A0, B0, T0, y0)
            ACCUM(A1, B1, T1, y1)
            ACCUM(A2, B2, T2, y2)
            ACCUM(A3, B3, T3, y3)
            y0 = n0; y1 = n1; y2 = n2; y3 = n3;
        }
    }

    // ---- rare tail (cnt > 32): redundant per-lane FiLM ----
    if (cnt > 32) {
        int be = bucket[(long)node * CAP + min(32 + u, CAP-1)];
        if (32 + u >= cnt) be = 0;
        for (int k = 32; k < cnt; ++k) {
            const int e = __shfl(be, k - 32, 32);
            const int s = eidx[e];
            const float4 ea = ((const float4*)(ee + (long)e * 8))[0];
            const float4 eb = ((const float4*)(ee + (long)e * 8))[1];
            const float4 at = ((const float4*)eattr)[e];
            const float eev[8] = {ea.x, ea.y, ea.z, ea.w, eb.x, eb.y, eb.z, eb.w};
            float h[8];
            #pragma unroll
            for (int j = 0; j < 8; ++j) {
                float pre = 0.f;
                #pragma unroll
                for (int b = 0; b < 8; ++b) pre += eev[b] * fcw1[b*8 + j];
                pre *= inv_sqrt8;
                h[j] = pre / (1.f + __expf(-pre)) * inv_sqrt8;
            }
            const float4 HA = make_float4(h[0], h[1], h[2], h[3]);
            const float4 HB = make_float4(h[4], h[5], h[6], h[7]);
            const uint2 y = *(const uint2*)(ysvh + (long)s * 128 + u * 4);
            ACCUM(HA, HB, at, y)
        }
    }
    #undef GATHER
    #undef ACCUM

    msb *= 0.5773502691896258f;  // INV_SQRT3

    // ---- lin2 epilogue via mid-LDS transpose (intra-group, no barrier) ----
    float* m = mid[nl];
    m[u]       = msa;
    m[32 + u]  = msb;
    m[64  + u*3 + 0] = va0;  m[64  + u*3 + 1] = va1;  m[64  + u*3 + 2] = va2;
    m[160 + u*3 + 0] = vb0;  m[160 + u*3 + 1] = vb1;  m[160 + u*3 + 2] = vb2;

    float os = 0.f, ov0 = 0.f, ov1 = 0.f, ov2 = 0.f;
    #pragma unroll 8
    for (int q = 0; q < 32; ++q) {
        const float wsa = W2s[q*32 + u];
        const float wsb = W2s[(32 + q)*32 + u];
        os += m[q] * wsa + m[32 + q] * wsb;
        const float wva = W2v[q*32 + u];
        const float wvb = W2v[(32 + q)*32 + u];
        ov0 += m[64 + q*3 + 0] * wva + m[160 + q*3 + 0] * wvb;
        ov1 += m[64 + q*3 + 1] * wva + m[160 + q*3 + 1] * wvb;
        ov2 += m[64 + q*3 + 2] * wva + m[160 + q*3 + 2] * wvb;
    }

    const float sc = 0.03125f;  // (1/sqrt 16) * (1/sqrt 64)
    float* op = out + (long)node * 128;
    op[u]            += os  * sc;
    op[32 + 3*u + 0] += ov0 * sc;
    op[32 + 3*u + 1] += ov1 * sc;
    op[32 + 3*u + 2] += ov2 * sc;
}

extern "C" void kernel_launch(void* const* d_in, const int* in_sizes, int n_in,
                              void* d_out, int out_size, void* d_ws, size_t ws_size,
                              hipStream_t stream) {
    const float* x     = (const float*)d_in[0];
    const float* attr  = (const float*)d_in[1];
    const float* ee    = (const float*)d_in[2];
    const float* eattr = (const float*)d_in[3];
    const int*   eidx  = (const int*)  d_in[4];
    const float* W1s   = (const float*)d_in[5];
    const float* W1v   = (const float*)d_in[6];
    const float* fcw1  = (const float*)d_in[7];
    const float* fcw2  = (const float*)d_in[8];
    const float* W2s   = (const float*)d_in[9];
    const float* W2v   = (const float*)d_in[10];
    const float* Wscs  = (const float*)d_in[11];
    const float* Wscv  = (const float*)d_in[12];

    float* out = (float*)d_out;

    // workspace layout (16-B aligned)
    unsigned short* ysvh = (unsigned short*)d_ws;            // 50000*128 bf16 = 12.8 MB
    int*   counts = (int*)(ysvh + (long)N_NODES * 128);      // 50000 i32
    int*   bucket = counts + N_NODES;                        // 50000*48 i32 = 9.6 MB

    hipMemsetAsync(counts, 0, N_NODES * sizeof(int), stream);
    prep_kernel<<<NODE_BLOCKS + BUCKET_BLOCKS, 256, 0, stream>>>(
        x, attr, W1s, W1v, Wscs, Wscv, eidx, counts, bucket, ysvh, out);
    agg_kernel<<<N_NODES/8, 256, 0, stream>>>(ee, eattr, eidx, fcw1, fcw2,
                                              W2s, W2v, ysvh, counts, bucket, out);
}

// Round 5
// 307.228 us; speedup vs baseline: 1.1026x; 1.1026x over previous
//
#include <hip/hip_runtime.h>
#include <hip/hip_bf16.h>

#define N_NODES 50000
#define N_EDGES 800000
#define CAP 48                       // max deg ~45 for Poisson(16) over 50K (48=8sigma)
#define NODE_BLOCKS 1250             // node-role blocks FIRST (5 batches of 8 nodes)
#define BUCKET_BLOCKS 1563           // ceil(400000/256), 2 edges/thread

__device__ __forceinline__ unsigned short f2bf(float f) {
    union { float f; unsigned u; } t; t.f = f;
    unsigned r = t.u + 0x7FFF + ((t.u >> 16) & 1);   // RNE
    return (unsigned short)(r >> 16);
}

// ---------------------------------------------------------------------------
// Fused prep, role-split. Roles overlap via co-residency: 1250 node blocks
// dispatch first (long-lived 5-batch loop), bucket blocks fill the rest of
// the machine immediately. (R4's 6250-node-first layout serialized the roles
// and cost +25 us; the 3-kernel split cost +45 us.)
//  node role: lin1 + self-connection — R1's best-measured config:
//    W1 columns in 64 VGPRs, x batch-staged in LDS (b128 broadcast reads),
//    Wsc in LDS (species-indexed, conflict-free b32).
//  bucket role: reverse-CSR build. Transaction-latency-bound (R4 counters:
//    VALU 11%, HBM 9%, occ 28% -> nothing saturated). 2 edges/thread = two
//    independent atomic->store chains per thread (isolated this round).
// ---------------------------------------------------------------------------
__global__ __launch_bounds__(256) void prep_kernel(
    const float* __restrict__ x, const float* __restrict__ attr,
    const float* __restrict__ W1s, const float* __restrict__ W1v,
    const float* __restrict__ Wscs, const float* __restrict__ Wscv,
    const int* __restrict__ eidx,
    int* __restrict__ counts, int* __restrict__ bucket,
    unsigned short* __restrict__ ysvh, float* __restrict__ out)
{
    // node role layout: x[0..1023] | Wscs[1024..5119] | Wscv[5120..9215]
    __shared__ float shm[9216];
    const int tid = threadIdx.x;

    if (blockIdx.x < NODE_BLOCKS) {
        // ---------------- node role ----------------
        const int nl = tid >> 5;
        const int w  = tid & 31;

        // W1 columns (column w, all u) in registers — loaded once, coalesced
        float w1s[32], w1v[32];
        #pragma unroll
        for (int u = 0; u < 32; ++u) {
            w1s[u] = W1s[u*32 + w];
            w1v[u] = W1v[u*32 + w];
        }
        // stage Wsc into LDS (1024 float4 each)
        #pragma unroll
        for (int i = 0; i < 4; ++i) {
            ((float4*)(shm + 1024))[tid + i*256] = ((const float4*)Wscs)[tid + i*256];
            ((float4*)(shm + 5120))[tid + i*256] = ((const float4*)Wscv)[tid + i*256];
        }

        const float l1n = 0.17677669529663687f;   // 1/sqrt(32)
        const float scn = 0.08838834764831843f;   // 1/sqrt(128)

        for (int batch = 0; batch < 5; ++batch) {
            const int node0 = blockIdx.x * 40 + batch * 8;
            __syncthreads();   // protect shm x-region (covers Wsc staging too)
            ((float4*)shm)[tid] = ((const float4*)(x + (long)node0 * 128))[tid];
            __syncthreads();

            const int node = node0 + nl;
            const float* at = attr + (long)node * 4;
            int sp = 0;
            if (at[1] > 0.5f) sp = 1;
            if (at[2] > 0.5f) sp = 2;
            if (at[3] > 0.5f) sp = 3;

            const float* lx   = shm + nl * 128;
            const float* lscs = shm + 1024 + sp * 32;
            const float* lscv = shm + 5120 + sp * 32;

            float ys = 0.f, yv0 = 0.f, yv1 = 0.f, yv2 = 0.f;
            float ss = 0.f, sv0 = 0.f, sv1 = 0.f, sv2 = 0.f;
            #pragma unroll
            for (int u4 = 0; u4 < 8; ++u4) {
                // broadcast b128 reads (all 32 lanes of the group, same addr)
                const float4 xs4 = ((const float4*)lx)[u4];
                const float4 q0  = ((const float4*)(lx + 32))[u4*3 + 0];
                const float4 q1  = ((const float4*)(lx + 32))[u4*3 + 1];
                const float4 q2  = ((const float4*)(lx + 32))[u4*3 + 2];
                const float xsv[4]  = {xs4.x, xs4.y, xs4.z, xs4.w};
                const float xvv[12] = {q0.x,q0.y,q0.z,q0.w,
                                       q1.x,q1.y,q1.z,q1.w,
                                       q2.x,q2.y,q2.z,q2.w};
                #pragma unroll
                for (int j = 0; j < 4; ++j) {
                    const int u = u4*4 + j;
                    const float wss = lscs[u*128 + w];   // conflict-free b32
                    const float wsv = lscv[u*128 + w];
                    ys  += xsv[j] * w1s[u];
                    yv0 += xvv[3*j+0] * w1v[u];
                    yv1 += xvv[3*j+1] * w1v[u];
                    yv2 += xvv[3*j+2] * w1v[u];
                    ss  += xsv[j] * wss;
                    sv0 += xvv[3*j+0] * wsv;
                    sv1 += xvv[3*j+1] * wsv;
                    sv2 += xvv[3*j+2] * wsv;
                }
            }

            uint2 pk;
            pk.x = (unsigned)f2bf(ys  * l1n) | ((unsigned)f2bf(yv0 * l1n) << 16);
            pk.y = (unsigned)f2bf(yv1 * l1n) | ((unsigned)f2bf(yv2 * l1n) << 16);
            *(uint2*)(ysvh + (long)node * 128 + w * 4) = pk;

            float* op = out + (long)node * 128;
            op[w] = ss * scn;
            op[32 + 3*w + 0] = sv0 * scn;
            op[32 + 3*w + 1] = sv1 * scn;
            op[32 + 3*w + 2] = sv2 * scn;
        }
    } else {
        // ---------------- bucket role (2 edges/thread, interleaved) --------
        const int gid = (blockIdx.x - NODE_BLOCKS) * 256 + tid;
        if (gid < N_EDGES/2) {
            const int d0 = eidx[N_EDGES + gid];
            const int d1 = eidx[N_EDGES + gid + N_EDGES/2];
            const int s0 = atomicAdd(&counts[d0], 1);
            const int s1 = atomicAdd(&counts[d1], 1);
            if (s0 < CAP) bucket[(long)d0 * CAP + s0] = gid;
            if (s1 < CAP) bucket[(long)d1 * CAP + s1] = gid + N_EDGES/2;
        }
    }
}

// ---------------------------------------------------------------------------
// Aggregation: 8 nodes / 256-thread block, 32 lanes per node-group. FiLM
// computed in-kernel lane-parallel (prologue) into LDS; loop body: broadcast
// ds_read of {h',attr} + prefetched ysv gathers ONLY. 4 edges/iter with the
// next 4 gathers in flight (depth-8 measured slower). Dummy slots gather
// node 0 (one hot L1 line) instead of a random src.
// ---------------------------------------------------------------------------
__global__ __launch_bounds__(256) void agg_kernel(
    const float* __restrict__ ee, const float* __restrict__ eattr,
    const int* __restrict__ eidx,
    const float* __restrict__ fcw1, const float* __restrict__ fcw2,
    const float* __restrict__ W2s, const float* __restrict__ W2v,
    const unsigned short* __restrict__ ysvh,
    const int* __restrict__ counts, const int* __restrict__ bucket,
    float* __restrict__ out)
{
    __shared__ float hrec[8][32 * 12];  // 12 KB: per group, per slot {h'[8], attr[4]}
    __shared__ float mid[8][256];       // 8 KB

    const int tid = threadIdx.x;
    const int nl = tid >> 5;
    const int u  = tid & 31;
    const int node = blockIdx.x * 8 + nl;
    const float inv_sqrt8 = 0.35355339059327373f;

    // fc2 fragment: f2r[j][q] = fcw2[j*128 + q*32 + u]
    float f2r[8][4];
    #pragma unroll
    for (int j = 0; j < 8; ++j) {
        f2r[j][0] = fcw2[j*128 + u];
        f2r[j][1] = fcw2[j*128 + 32 + u];
        f2r[j][2] = fcw2[j*128 + 64 + u];
        f2r[j][3] = fcw2[j*128 + 96 + u];
    }

    const int cnt = min(counts[node], CAP);
    int e0 = bucket[(long)node * CAP + u];   // u<32<CAP, safe
    const bool dummy = (u >= cnt);
    if (dummy) e0 = 0;
    const int s0 = dummy ? 0 : eidx[e0];   // dummy gathers hit node 0 (hot line)

    // ---- prologue: lane u computes FiLM h' for its own slot's edge ----
    {
        const float4 ea = ((const float4*)(ee + (long)e0 * 8))[0];
        const float4 eb = ((const float4*)(ee + (long)e0 * 8))[1];
        const float4 at = ((const float4*)eattr)[e0];
        const float eev[8] = {ea.x, ea.y, ea.z, ea.w, eb.x, eb.y, eb.z, eb.w};
        float* hr = hrec[nl] + u * 12;
        float h[8];
        #pragma unroll
        for (int j = 0; j < 8; ++j) {
            float pre = 0.f;
            #pragma unroll
            for (int b = 0; b < 8; ++b) pre += eev[b] * fcw1[b*8 + j];
            pre *= inv_sqrt8;
            const float s = pre / (1.f + __expf(-pre)) * inv_sqrt8;
            h[j] = dummy ? 0.f : s;     // h'=0 kills every term of a dummy slot
        }
        ((float4*)hr)[0] = make_float4(h[0], h[1], h[2], h[3]);
        ((float4*)hr)[1] = make_float4(h[4], h[5], h[6], h[7]);
        ((float4*)hr)[2] = at;
        // no barrier: written and read by the same 32-lane group (wave-sync)
    }

    float msa = 0.f, msb = 0.f;
    float va0 = 0.f, va1 = 0.f, va2 = 0.f;
    float vb0 = 0.f, vb1 = 0.f, vb2 = 0.f;

    #define ACCUM(HA, HB, AT, Y)                                             \
    {                                                                        \
        const float es = __uint_as_float((Y).x << 16);                       \
        const float ex = __uint_as_float((Y).x & 0xffff0000u);               \
        const float ey = __uint_as_float((Y).y << 16);                       \
        const float ez = __uint_as_float((Y).y & 0xffff0000u);               \
        const float hh[8] = {HA.x,HA.y,HA.z,HA.w,HB.x,HB.y,HB.z,HB.w};       \
        float w00=0.f, w01=0.f, w10=0.f, w11=0.f;                            \
        _Pragma("unroll")                                                    \
        for (int j = 0; j < 8; ++j) {                                        \
            w00 += hh[j]*f2r[j][0]; w01 += hh[j]*f2r[j][1];                  \
            w10 += hh[j]*f2r[j][2]; w11 += hh[j]*f2r[j][3];                  \
        }                                                                    \
        const float a0 = AT.x, a1x = AT.y, a1y = AT.z, a1z = AT.w;           \
        msa += w00 * es * a0;                                                \
        msb += w11 * (ex*a1x + ey*a1y + ez*a1z);                             \
        const float t = w01 * es;                                            \
        va0 += t*a1x; va1 += t*a1y; va2 += t*a1z;                            \
        const float s = w10 * a0;                                            \
        vb0 += s*ex; vb1 += s*ey; vb2 += s*ez;                               \
    }

    #define GATHER(SLOT) \
        (*(const uint2*)(ysvh + (long)__shfl(s0, (SLOT), 32) * 128 + u * 4))

    // ---- main loop: 4 edges/iter, next 4 gathers in flight ----
    const int c0 = min(cnt, 32);
    {
        uint2 y0 = GATHER(0), y1 = GATHER(1), y2 = GATHER(2), y3 = GATHER(3);
        for (int k = 0; k < c0; k += 4) {
            const int kn = (k + 4) & 31;            // wrap: dummy-safe
            const uint2 n0 = GATHER(kn);
            const uint2 n1 = GATHER(kn + 1);
            const uint2 n2 = GATHER(kn + 2);
            const uint2 n3 = GATHER(kn + 3);
            const float4* h0p = (const float4*)(hrec[nl] + (k + 0) * 12);
            const float4* h1p = (const float4*)(hrec[nl] + (k + 1) * 12);
            const float4* h2p = (const float4*)(hrec[nl] + (k + 2) * 12);
            const float4* h3p = (const float4*)(hrec[nl] + (k + 3) * 12);
            const float4 A0 = h0p[0], B0 = h0p[1], T0 = h0p[2];
            const float4 A1 = h1p[0], B1 = h1p[1], T1 = h1p[2];
            const float4 A2 = h2p[0], B2 = h2p[1], T2 = h2p[2];
            const float4 A3 = h3p[0], B3 = h3p[1], T3 = h3p[2];
            ACCUM(A0, B0, T0, y0)
            ACCUM(A1, B1, T1, y1)
            ACCUM(A2, B2, T2, y2)
            ACCUM(A3, B3, T3, y3)
            y0 = n0; y1 = n1; y2 = n2; y3 = n3;
        }
    }

    // ---- rare tail (cnt > 32): redundant per-lane FiLM ----
    if (cnt > 32) {
        int be = bucket[(long)node * CAP + min(32 + u, CAP-1)];
        if (32 + u >= cnt) be = 0;
        for (int k = 32; k < cnt; ++k) {
            const int e = __shfl(be, k - 32, 32);
            const int s = eidx[e];
            const float4 ea = ((const float4*)(ee + (long)e * 8))[0];
            const float4 eb = ((const float4*)(ee + (long)e * 8))[1];
            const float4 at = ((const float4*)eattr)[e];
            const float eev[8] = {ea.x, ea.y, ea.z, ea.w, eb.x, eb.y, eb.z, eb.w};
            float h[8];
            #pragma unroll
            for (int j = 0; j < 8; ++j) {
                float pre = 0.f;
                #pragma unroll
                for (int b = 0; b < 8; ++b) pre += eev[b] * fcw1[b*8 + j];
                pre *= inv_sqrt8;
                h[j] = pre / (1.f + __expf(-pre)) * inv_sqrt8;
            }
            const float4 HA = make_float4(h[0], h[1], h[2], h[3]);
            const float4 HB = make_float4(h[4], h[5], h[6], h[7]);
            const uint2 y = *(const uint2*)(ysvh + (long)s * 128 + u * 4);
            ACCUM(HA, HB, at, y)
        }
    }
    #undef GATHER
    #undef ACCUM

    msb *= 0.5773502691896258f;  // INV_SQRT3

    // ---- lin2 epilogue via mid-LDS transpose (intra-group, no barrier) ----
    float* m = mid[nl];
    m[u]       = msa;
    m[32 + u]  = msb;
    m[64  + u*3 + 0] = va0;  m[64  + u*3 + 1] = va1;  m[64  + u*3 + 2] = va2;
    m[160 + u*3 + 0] = vb0;  m[160 + u*3 + 1] = vb1;  m[160 + u*3 + 2] = vb2;

    float os = 0.f, ov0 = 0.f, ov1 = 0.f, ov2 = 0.f;
    #pragma unroll 8
    for (int q = 0; q < 32; ++q) {
        const float wsa = W2s[q*32 + u];
        const float wsb = W2s[(32 + q)*32 + u];
        os += m[q] * wsa + m[32 + q] * wsb;
        const float wva = W2v[q*32 + u];
        const float wvb = W2v[(32 + q)*32 + u];
        ov0 += m[64 + q*3 + 0] * wva + m[160 + q*3 + 0] * wvb;
        ov1 += m[64 + q*3 + 1] * wva + m[160 + q*3 + 1] * wvb;
        ov2 += m[64 + q*3 + 2] * wva + m[160 + q*3 + 2] * wvb;
    }

    const float sc = 0.03125f;  // (1/sqrt 16) * (1/sqrt 64)
    float* op = out + (long)node * 128;
    op[u]            += os  * sc;
    op[32 + 3*u + 0] += ov0 * sc;
    op[32 + 3*u + 1] += ov1 * sc;
    op[32 + 3*u + 2] += ov2 * sc;
}

extern "C" void kernel_launch(void* const* d_in, const int* in_sizes, int n_in,
                              void* d_out, int out_size, void* d_ws, size_t ws_size,
                              hipStream_t stream) {
    const float* x     = (const float*)d_in[0];
    const float* attr  = (const float*)d_in[1];
    const float* ee    = (const float*)d_in[2];
    const float* eattr = (const float*)d_in[3];
    const int*   eidx  = (const int*)  d_in[4];
    const float* W1s   = (const float*)d_in[5];
    const float* W1v   = (const float*)d_in[6];
    const float* fcw1  = (const float*)d_in[7];
    const float* fcw2  = (const float*)d_in[8];
    const float* W2s   = (const float*)d_in[9];
    const float* W2v   = (const float*)d_in[10];
    const float* Wscs  = (const float*)d_in[11];
    const float* Wscv  = (const float*)d_in[12];

    float* out = (float*)d_out;

    // workspace layout (16-B aligned)
    unsigned short* ysvh = (unsigned short*)d_ws;            // 50000*128 bf16 = 12.8 MB
    int*   counts = (int*)(ysvh + (long)N_NODES * 128);      // 50000 i32
    int*   bucket = counts + N_NODES;                        // 50000*48 i32 = 9.6 MB

    hipMemsetAsync(counts, 0, N_NODES * sizeof(int), stream);
    prep_kernel<<<NODE_BLOCKS + BUCKET_BLOCKS, 256, 0, stream>>>(
        x, attr, W1s, W1v, Wscs, Wscv, eidx, counts, bucket, ysvh, out);
    agg_kernel<<<N_NODES/8, 256, 0, stream>>>(ee, eattr, eidx, fcw1, fcw2,
                                              W2s, W2v, ysvh, counts, bucket, out);
}

// Round 6
// 298.964 us; speedup vs baseline: 1.1330x; 1.0276x over previous
//
#include <hip/hip_runtime.h>
#include <hip/hip_bf16.h>

#define N_NODES 50000
#define N_EDGES 800000
#define CAP 64                       // max deg ~45 for Poisson(16) over 50K
#define NODE_BLOCKS 1250             // node-role blocks FIRST (5 batches of 8 nodes)
#define BUCKET_BLOCKS (N_EDGES/256)  // 3125 exact, 1 edge/thread

__device__ __forceinline__ unsigned short f2bf(float f) {
    union { float f; unsigned u; } t; t.f = f;
    unsigned r = t.u + 0x7FFF + ((t.u >> 16) & 1);   // RNE
    return (unsigned short)(r >> 16);
}

// ---------------------------------------------------------------------------
// Fused prep, role-split. Roles overlap via co-residency: 1250 node blocks
// first (long-lived 5-batch loop), bucket blocks fill the machine behind
// them. Config = R1's measured-best (prep+ovh 161 us):
//  node role: W1 columns in 64 VGPRs; x batch-staged in LDS (b128 broadcast
//    reads); Wsc in LDS (species-indexed, conflict-free b32).
//  bucket role: reverse-CSR build, 1 edge/thread, CAP 64, compact counts.
//    (Measured dead ends: 2-edge/thread +31 us — halves bucket wave count
//    while LDS-capped at 4 blocks/CU; 64B-line count padding neutral;
//    3-kernel split +45 us; 6250-node-first layout +25 us.)
// ---------------------------------------------------------------------------
__global__ __launch_bounds__(256) void prep_kernel(
    const float* __restrict__ x, const float* __restrict__ attr,
    const float* __restrict__ W1s, const float* __restrict__ W1v,
    const float* __restrict__ Wscs, const float* __restrict__ Wscv,
    const int* __restrict__ eidx,
    int* __restrict__ counts, int* __restrict__ bucket,
    unsigned short* __restrict__ ysvh, float* __restrict__ out)
{
    // node role layout: x[0..1023] | Wscs[1024..5119] | Wscv[5120..9215]
    __shared__ float shm[9216];
    const int tid = threadIdx.x;

    if (blockIdx.x < NODE_BLOCKS) {
        // ---------------- node role ----------------
        const int nl = tid >> 5;
        const int w  = tid & 31;

        // W1 columns (column w, all u) in registers — loaded once, coalesced
        float w1s[32], w1v[32];
        #pragma unroll
        for (int u = 0; u < 32; ++u) {
            w1s[u] = W1s[u*32 + w];
            w1v[u] = W1v[u*32 + w];
        }
        // stage Wsc into LDS (1024 float4 each)
        #pragma unroll
        for (int i = 0; i < 4; ++i) {
            ((float4*)(shm + 1024))[tid + i*256] = ((const float4*)Wscs)[tid + i*256];
            ((float4*)(shm + 5120))[tid + i*256] = ((const float4*)Wscv)[tid + i*256];
        }

        const float l1n = 0.17677669529663687f;   // 1/sqrt(32)
        const float scn = 0.08838834764831843f;   // 1/sqrt(128)

        for (int batch = 0; batch < 5; ++batch) {
            const int node0 = blockIdx.x * 40 + batch * 8;
            __syncthreads();   // protect shm x-region (covers Wsc staging too)
            ((float4*)shm)[tid] = ((const float4*)(x + (long)node0 * 128))[tid];
            __syncthreads();

            const int node = node0 + nl;
            const float* at = attr + (long)node * 4;
            int sp = 0;
            if (at[1] > 0.5f) sp = 1;
            if (at[2] > 0.5f) sp = 2;
            if (at[3] > 0.5f) sp = 3;

            const float* lx   = shm + nl * 128;
            const float* lscs = shm + 1024 + sp * 32;
            const float* lscv = shm + 5120 + sp * 32;

            float ys = 0.f, yv0 = 0.f, yv1 = 0.f, yv2 = 0.f;
            float ss = 0.f, sv0 = 0.f, sv1 = 0.f, sv2 = 0.f;
            #pragma unroll
            for (int u4 = 0; u4 < 8; ++u4) {
                // broadcast b128 reads (all 32 lanes of the group, same addr)
                const float4 xs4 = ((const float4*)lx)[u4];
                const float4 q0  = ((const float4*)(lx + 32))[u4*3 + 0];
                const float4 q1  = ((const float4*)(lx + 32))[u4*3 + 1];
                const float4 q2  = ((const float4*)(lx + 32))[u4*3 + 2];
                const float xsv[4]  = {xs4.x, xs4.y, xs4.z, xs4.w};
                const float xvv[12] = {q0.x,q0.y,q0.z,q0.w,
                                       q1.x,q1.y,q1.z,q1.w,
                                       q2.x,q2.y,q2.z,q2.w};
                #pragma unroll
                for (int j = 0; j < 4; ++j) {
                    const int u = u4*4 + j;
                    const float wss = lscs[u*128 + w];   // conflict-free b32
                    const float wsv = lscv[u*128 + w];
                    ys  += xsv[j] * w1s[u];
                    yv0 += xvv[3*j+0] * w1v[u];
                    yv1 += xvv[3*j+1] * w1v[u];
                    yv2 += xvv[3*j+2] * w1v[u];
                    ss  += xsv[j] * wss;
                    sv0 += xvv[3*j+0] * wsv;
                    sv1 += xvv[3*j+1] * wsv;
                    sv2 += xvv[3*j+2] * wsv;
                }
            }

            uint2 pk;
            pk.x = (unsigned)f2bf(ys  * l1n) | ((unsigned)f2bf(yv0 * l1n) << 16);
            pk.y = (unsigned)f2bf(yv1 * l1n) | ((unsigned)f2bf(yv2 * l1n) << 16);
            *(uint2*)(ysvh + (long)node * 128 + w * 4) = pk;

            float* op = out + (long)node * 128;
            op[w] = ss * scn;
            op[32 + 3*w + 0] = sv0 * scn;
            op[32 + 3*w + 1] = sv1 * scn;
            op[32 + 3*w + 2] = sv2 * scn;
        }
    } else {
        // ---------------- bucket role (1 edge/thread) ----------------
        const int e = (blockIdx.x - NODE_BLOCKS) * 256 + tid;
        const int dst = eidx[N_EDGES + e];
        const int slot = atomicAdd(&counts[dst], 1);
        if (slot < CAP) bucket[(long)dst * CAP + slot] = e;
    }
}

// ---------------------------------------------------------------------------
// Aggregation: 8 nodes / 256-thread block, 32 lanes per node-group. FiLM
// computed in-kernel lane-parallel (prologue) into LDS; loop body: broadcast
// ds_read of {h',attr} + prefetched ysv gathers ONLY. 4 edges/iter with the
// next 4 gathers in flight (depth-8 measured slower). Dummy slots gather
// node 0 (one hot L1 line). v6: mid UNIONED into hrec (mid's 256 floats fit
// hrec's 384/group; loop's last hrec read precedes all mid writes within the
// wave; groups own disjoint regions) -> LDS 20.5 KB -> 12 KB.
// ---------------------------------------------------------------------------
__global__ __launch_bounds__(256) void agg_kernel(
    const float* __restrict__ ee, const float* __restrict__ eattr,
    const int* __restrict__ eidx,
    const float* __restrict__ fcw1, const float* __restrict__ fcw2,
    const float* __restrict__ W2s, const float* __restrict__ W2v,
    const unsigned short* __restrict__ ysvh,
    const int* __restrict__ counts, const int* __restrict__ bucket,
    float* __restrict__ out)
{
    __shared__ float hrec[8][32 * 12];  // 12 KB: {h'[8], attr[4]} per slot; reused as mid

    const int tid = threadIdx.x;
    const int nl = tid >> 5;
    const int u  = tid & 31;
    const int node = blockIdx.x * 8 + nl;
    const float inv_sqrt8 = 0.35355339059327373f;

    // fc2 fragment: f2r[j][q] = fcw2[j*128 + q*32 + u]
    float f2r[8][4];
    #pragma unroll
    for (int j = 0; j < 8; ++j) {
        f2r[j][0] = fcw2[j*128 + u];
        f2r[j][1] = fcw2[j*128 + 32 + u];
        f2r[j][2] = fcw2[j*128 + 64 + u];
        f2r[j][3] = fcw2[j*128 + 96 + u];
    }

    const int cnt = min(counts[node], CAP);
    int e0 = bucket[(long)node * CAP + u];
    const bool dummy = (u >= cnt);
    if (dummy) e0 = 0;
    const int s0 = dummy ? 0 : eidx[e0];   // dummy gathers hit node 0 (hot line)

    // ---- prologue: lane u computes FiLM h' for its own slot's edge ----
    {
        const float4 ea = ((const float4*)(ee + (long)e0 * 8))[0];
        const float4 eb = ((const float4*)(ee + (long)e0 * 8))[1];
        const float4 at = ((const float4*)eattr)[e0];
        const float eev[8] = {ea.x, ea.y, ea.z, ea.w, eb.x, eb.y, eb.z, eb.w};
        float* hr = hrec[nl] + u * 12;
        float h[8];
        #pragma unroll
        for (int j = 0; j < 8; ++j) {
            float pre = 0.f;
            #pragma unroll
            for (int b = 0; b < 8; ++b) pre += eev[b] * fcw1[b*8 + j];
            pre *= inv_sqrt8;
            const float s = pre / (1.f + __expf(-pre)) * inv_sqrt8;
            h[j] = dummy ? 0.f : s;     // h'=0 kills every term of a dummy slot
        }
        ((float4*)hr)[0] = make_float4(h[0], h[1], h[2], h[3]);
        ((float4*)hr)[1] = make_float4(h[4], h[5], h[6], h[7]);
        ((float4*)hr)[2] = at;
        // no barrier: written and read by the same 32-lane group (wave-sync)
    }

    float msa = 0.f, msb = 0.f;
    float va0 = 0.f, va1 = 0.f, va2 = 0.f;
    float vb0 = 0.f, vb1 = 0.f, vb2 = 0.f;

    #define ACCUM(HA, HB, AT, Y)                                             \
    {                                                                        \
        const float es = __uint_as_float((Y).x << 16);                       \
        const float ex = __uint_as_float((Y).x & 0xffff0000u);               \
        const float ey = __uint_as_float((Y).y << 16);                       \
        const float ez = __uint_as_float((Y).y & 0xffff0000u);               \
        const float hh[8] = {HA.x,HA.y,HA.z,HA.w,HB.x,HB.y,HB.z,HB.w};       \
        float w00=0.f, w01=0.f, w10=0.f, w11=0.f;                            \
        _Pragma("unroll")                                                    \
        for (int j = 0; j < 8; ++j) {                                        \
            w00 += hh[j]*f2r[j][0]; w01 += hh[j]*f2r[j][1];                  \
            w10 += hh[j]*f2r[j][2]; w11 += hh[j]*f2r[j][3];                  \
        }                                                                    \
        const float a0 = AT.x, a1x = AT.y, a1y = AT.z, a1z = AT.w;           \
        msa += w00 * es * a0;                                                \
        msb += w11 * (ex*a1x + ey*a1y + ez*a1z);                             \
        const float t = w01 * es;                                            \
        va0 += t*a1x; va1 += t*a1y; va2 += t*a1z;                            \
        const float s = w10 * a0;                                            \
        vb0 += s*ex; vb1 += s*ey; vb2 += s*ez;                               \
    }

    #define GATHER(SLOT) \
        (*(const uint2*)(ysvh + (long)__shfl(s0, (SLOT), 32) * 128 + u * 4))

    // ---- main loop: 4 edges/iter, next 4 gathers in flight ----
    const int c0 = min(cnt, 32);
    {
        uint2 y0 = GATHER(0), y1 = GATHER(1), y2 = GATHER(2), y3 = GATHER(3);
        for (int k = 0; k < c0; k += 4) {
            const int kn = (k + 4) & 31;            // wrap: dummy-safe
            const uint2 n0 = GATHER(kn);
            const uint2 n1 = GATHER(kn + 1);
            const uint2 n2 = GATHER(kn + 2);
            const uint2 n3 = GATHER(kn + 3);
            const float4* h0p = (const float4*)(hrec[nl] + (k + 0) * 12);
            const float4* h1p = (const float4*)(hrec[nl] + (k + 1) * 12);
            const float4* h2p = (const float4*)(hrec[nl] + (k + 2) * 12);
            const float4* h3p = (const float4*)(hrec[nl] + (k + 3) * 12);
            const float4 A0 = h0p[0], B0 = h0p[1], T0 = h0p[2];
            const float4 A1 = h1p[0], B1 = h1p[1], T1 = h1p[2];
            const float4 A2 = h2p[0], B2 = h2p[1], T2 = h2p[2];
            const float4 A3 = h3p[0], B3 = h3p[1], T3 = h3p[2];
            ACCUM(A0, B0, T0, y0)
            ACCUM(A1, B1, T1, y1)
            ACCUM(A2, B2, T2, y2)
            ACCUM(A3, B3, T3, y3)
            y0 = n0; y1 = n1; y2 = n2; y3 = n3;
        }
    }

    // ---- rare tail (cnt > 32): redundant per-lane FiLM ----
    if (cnt > 32) {
        int be = bucket[(long)node * CAP + min(32 + u, CAP-1)];
        if (32 + u >= cnt) be = 0;
        for (int k = 32; k < cnt; ++k) {
            const int e = __shfl(be, k - 32, 32);
            const int s = eidx[e];
            const float4 ea = ((const float4*)(ee + (long)e * 8))[0];
            const float4 eb = ((const float4*)(ee + (long)e * 8))[1];
            const float4 at = ((const float4*)eattr)[e];
            const float eev[8] = {ea.x, ea.y, ea.z, ea.w, eb.x, eb.y, eb.z, eb.w};
            float h[8];
            #pragma unroll
            for (int j = 0; j < 8; ++j) {
                float pre = 0.f;
                #pragma unroll
                for (int b = 0; b < 8; ++b) pre += eev[b] * fcw1[b*8 + j];
                pre *= inv_sqrt8;
                h[j] = pre / (1.f + __expf(-pre)) * inv_sqrt8;
            }
            const float4 HA = make_float4(h[0], h[1], h[2], h[3]);
            const float4 HB = make_float4(h[4], h[5], h[6], h[7]);
            const uint2 y = *(const uint2*)(ysvh + (long)s * 128 + u * 4);
            ACCUM(HA, HB, at, y)
        }
    }
    #undef GATHER
    #undef ACCUM

    msb *= 0.5773502691896258f;  // INV_SQRT3

    // ---- lin2 epilogue: mid transpose REUSES hrec[nl] (disjoint phases,
    //      wave-lockstep: all lanes of the wave exited the loop) ----
    float* m = hrec[nl];
    m[u]       = msa;
    m[32 + u]  = msb;
    m[64  + u*3 + 0] = va0;  m[64  + u*3 + 1] = va1;  m[64  + u*3 + 2] = va2;
    m[160 + u*3 + 0] = vb0;  m[160 + u*3 + 1] = vb1;  m[160 + u*3 + 2] = vb2;

    float os = 0.f, ov0 = 0.f, ov1 = 0.f, ov2 = 0.f;
    #pragma unroll 8
    for (int q = 0; q < 32; ++q) {
        const float wsa = W2s[q*32 + u];
        const float wsb = W2s[(32 + q)*32 + u];
        os += m[q] * wsa + m[32 + q] * wsb;
        const float wva = W2v[q*32 + u];
        const float wvb = W2v[(32 + q)*32 + u];
        ov0 += m[64 + q*3 + 0] * wva + m[160 + q*3 + 0] * wvb;
        ov1 += m[64 + q*3 + 1] * wva + m[160 + q*3 + 1] * wvb;
        ov2 += m[64 + q*3 + 2] * wva + m[160 + q*3 + 2] * wvb;
    }

    const float sc = 0.03125f;  // (1/sqrt 16) * (1/sqrt 64)
    float* op = out + (long)node * 128;
    op[u]            += os  * sc;
    op[32 + 3*u + 0] += ov0 * sc;
    op[32 + 3*u + 1] += ov1 * sc;
    op[32 + 3*u + 2] += ov2 * sc;
}

extern "C" void kernel_launch(void* const* d_in, const int* in_sizes, int n_in,
                              void* d_out, int out_size, void* d_ws, size_t ws_size,
                              hipStream_t stream) {
    const float* x     = (const float*)d_in[0];
    const float* attr  = (const float*)d_in[1];
    const float* ee    = (const float*)d_in[2];
    const float* eattr = (const float*)d_in[3];
    const int*   eidx  = (const int*)  d_in[4];
    const float* W1s   = (const float*)d_in[5];
    const float* W1v   = (const float*)d_in[6];
    const float* fcw1  = (const float*)d_in[7];
    const float* fcw2  = (const float*)d_in[8];
    const float* W2s   = (const float*)d_in[9];
    const float* W2v   = (const float*)d_in[10];
    const float* Wscs  = (const float*)d_in[11];
    const float* Wscv  = (const float*)d_in[12];

    float* out = (float*)d_out;

    // workspace layout (16-B aligned)
    unsigned short* ysvh = (unsigned short*)d_ws;            // 50000*128 bf16 = 12.8 MB
    int*   counts = (int*)(ysvh + (long)N_NODES * 128);      // 50000 i32
    int*   bucket = counts + N_NODES;                        // 50000*64 i32 = 12.8 MB

    hipMemsetAsync(counts, 0, N_NODES * sizeof(int), stream);
    prep_kernel<<<NODE_BLOCKS + BUCKET_BLOCKS, 256, 0, stream>>>(
        x, attr, W1s, W1v, Wscs, Wscv, eidx, counts, bucket, ysvh, out);
    agg_kernel<<<N_NODES/8, 256, 0, stream>>>(ee, eattr, eidx, fcw1, fcw2,
                                              W2s, W2v, ysvh, counts, bucket, out);
}

// Round 7
// 275.608 us; speedup vs baseline: 1.2291x; 1.0847x over previous
//
#include <hip/hip_runtime.h>
#include <hip/hip_bf16.h>

#define N_NODES 50000
#define N_EDGES 800000
#define CAP 64                       // max deg ~45 for Poisson(16) over 50K
#define NODE_BLOCKS 1250             // node-role blocks FIRST (5 batches of 8 nodes)
#define BUCKET_BLOCKS (N_EDGES/256)  // 3125 exact, 1 edge/thread

__device__ __forceinline__ unsigned short f2bf(float f) {
    union { float f; unsigned u; } t; t.f = f;
    unsigned r = t.u + 0x7FFF + ((t.u >> 16) & 1);   // RNE
    return (unsigned short)(r >> 16);
}

// ---------------------------------------------------------------------------
// Fused prep, role-split. Roles overlap via co-residency: 1250 node blocks
// first (long-lived 5-batch loop), bucket blocks fill the machine behind.
//  node role: W1 columns in 64 VGPRs; x batch-staged in LDS (b128 broadcast
//    reads); Wsc in LDS (species-indexed, conflict-free b32).
//  bucket role: reverse-CSR build, 1 edge/thread, CAP 64 (measured best).
//    v7 (EP): ALSO computes FiLM h'[8] here (e sequential -> ee/eattr reads
//    coalesced; role was 11% VALU -> free compute) and streams a 64B/edge
//    record epay[e] = {h'[8] f32, attr[4] f32, src}. agg then reads ONE
//    aligned line per edge instead of 3 random lines (eidx+ee+eattr) + MLP.
//  (Measured dead ends: 2-edge/thread +31 us; count-line padding neutral;
//   3-kernel split +45 us; 6250-node-first +25 us; hrec/mid union neutral.)
// ---------------------------------------------------------------------------
template<bool EP>
__global__ __launch_bounds__(256) void prep_kernel(
    const float* __restrict__ x, const float* __restrict__ attr,
    const float* __restrict__ W1s, const float* __restrict__ W1v,
    const float* __restrict__ Wscs, const float* __restrict__ Wscv,
    const float* __restrict__ ee, const float* __restrict__ eattr,
    const float* __restrict__ fcw1,
    const int* __restrict__ eidx,
    int* __restrict__ counts, int* __restrict__ bucket,
    float* __restrict__ epay,
    unsigned short* __restrict__ ysvh, float* __restrict__ out)
{
    // node role layout: x[0..1023] | Wscs[1024..5119] | Wscv[5120..9215]
    __shared__ float shm[9216];
    const int tid = threadIdx.x;

    if (blockIdx.x < NODE_BLOCKS) {
        // ---------------- node role ----------------
        const int nl = tid >> 5;
        const int w  = tid & 31;

        // W1 columns (column w, all u) in registers — loaded once, coalesced
        float w1s[32], w1v[32];
        #pragma unroll
        for (int u = 0; u < 32; ++u) {
            w1s[u] = W1s[u*32 + w];
            w1v[u] = W1v[u*32 + w];
        }
        // stage Wsc into LDS (1024 float4 each)
        #pragma unroll
        for (int i = 0; i < 4; ++i) {
            ((float4*)(shm + 1024))[tid + i*256] = ((const float4*)Wscs)[tid + i*256];
            ((float4*)(shm + 5120))[tid + i*256] = ((const float4*)Wscv)[tid + i*256];
        }

        const float l1n = 0.17677669529663687f;   // 1/sqrt(32)
        const float scn = 0.08838834764831843f;   // 1/sqrt(128)

        for (int batch = 0; batch < 5; ++batch) {
            const int node0 = blockIdx.x * 40 + batch * 8;
            __syncthreads();   // protect shm x-region (covers Wsc staging too)
            ((float4*)shm)[tid] = ((const float4*)(x + (long)node0 * 128))[tid];
            __syncthreads();

            const int node = node0 + nl;
            const float* at = attr + (long)node * 4;
            int sp = 0;
            if (at[1] > 0.5f) sp = 1;
            if (at[2] > 0.5f) sp = 2;
            if (at[3] > 0.5f) sp = 3;

            const float* lx   = shm + nl * 128;
            const float* lscs = shm + 1024 + sp * 32;
            const float* lscv = shm + 5120 + sp * 32;

            float ys = 0.f, yv0 = 0.f, yv1 = 0.f, yv2 = 0.f;
            float ss = 0.f, sv0 = 0.f, sv1 = 0.f, sv2 = 0.f;
            #pragma unroll
            for (int u4 = 0; u4 < 8; ++u4) {
                // broadcast b128 reads (all 32 lanes of the group, same addr)
                const float4 xs4 = ((const float4*)lx)[u4];
                const float4 q0  = ((const float4*)(lx + 32))[u4*3 + 0];
                const float4 q1  = ((const float4*)(lx + 32))[u4*3 + 1];
                const float4 q2  = ((const float4*)(lx + 32))[u4*3 + 2];
                const float xsv[4]  = {xs4.x, xs4.y, xs4.z, xs4.w};
                const float xvv[12] = {q0.x,q0.y,q0.z,q0.w,
                                       q1.x,q1.y,q1.z,q1.w,
                                       q2.x,q2.y,q2.z,q2.w};
                #pragma unroll
                for (int j = 0; j < 4; ++j) {
                    const int u = u4*4 + j;
                    const float wss = lscs[u*128 + w];   // conflict-free b32
                    const float wsv = lscv[u*128 + w];
                    ys  += xsv[j] * w1s[u];
                    yv0 += xvv[3*j+0] * w1v[u];
                    yv1 += xvv[3*j+1] * w1v[u];
                    yv2 += xvv[3*j+2] * w1v[u];
                    ss  += xsv[j] * wss;
                    sv0 += xvv[3*j+0] * wsv;
                    sv1 += xvv[3*j+1] * wsv;
                    sv2 += xvv[3*j+2] * wsv;
                }
            }

            uint2 pk;
            pk.x = (unsigned)f2bf(ys  * l1n) | ((unsigned)f2bf(yv0 * l1n) << 16);
            pk.y = (unsigned)f2bf(yv1 * l1n) | ((unsigned)f2bf(yv2 * l1n) << 16);
            *(uint2*)(ysvh + (long)node * 128 + w * 4) = pk;

            float* op = out + (long)node * 128;
            op[w] = ss * scn;
            op[32 + 3*w + 0] = sv0 * scn;
            op[32 + 3*w + 1] = sv1 * scn;
            op[32 + 3*w + 2] = sv2 * scn;
        }
    } else {
        // ---------------- bucket role (1 edge/thread) ----------------
        const int e = (blockIdx.x - NODE_BLOCKS) * 256 + tid;
        const int dst = eidx[N_EDGES + e];
        if (EP) {
            const float inv_sqrt8 = 0.35355339059327373f;
            const int src = eidx[e];                               // coalesced
            const float4 ea = ((const float4*)(ee + (long)e * 8))[0];   // coalesced
            const float4 eb = ((const float4*)(ee + (long)e * 8))[1];
            const float4 at = ((const float4*)eattr)[e];                // coalesced
            const float eev[8] = {ea.x, ea.y, ea.z, ea.w, eb.x, eb.y, eb.z, eb.w};
            float h[8];
            #pragma unroll
            for (int j = 0; j < 8; ++j) {
                float pre = 0.f;
                #pragma unroll
                for (int b = 0; b < 8; ++b) pre += eev[b] * fcw1[b*8 + j];
                pre *= inv_sqrt8;
                h[j] = pre / (1.f + __expf(-pre)) * inv_sqrt8;
            }
            float4* ep = (float4*)(epay + (long)e * 16);   // 64B/edge, streaming
            ep[0] = make_float4(h[0], h[1], h[2], h[3]);
            ep[1] = make_float4(h[4], h[5], h[6], h[7]);
            ep[2] = at;
            ep[3] = make_float4(__int_as_float(src), 0.f, 0.f, 0.f);
        }
        const int slot = atomicAdd(&counts[dst], 1);
        if (slot < CAP) bucket[(long)dst * CAP + slot] = e;
    }
}

// ---------------------------------------------------------------------------
// Aggregation: 8 nodes / 256-thread block, 32 lanes per node-group. 4
// edges/iter with next 4 gathers in flight (depth-8 measured slower). Dummy
// slots gather node 0 (hot line). v7 (EP): prologue/tail read the 64B epay
// record (h', attr, src) — one aligned line per edge — instead of
// eidx+ee+eattr (3 random lines) + recomputing the FiLM MLP.
// ---------------------------------------------------------------------------
template<bool EP>
__global__ __launch_bounds__(256) void agg_kernel(
    const float* __restrict__ ee, const float* __restrict__ eattr,
    const int* __restrict__ eidx,
    const float* __restrict__ fcw1, const float* __restrict__ fcw2,
    const float* __restrict__ W2s, const float* __restrict__ W2v,
    const unsigned short* __restrict__ ysvh,
    const int* __restrict__ counts, const int* __restrict__ bucket,
    const float* __restrict__ epay,
    float* __restrict__ out)
{
    __shared__ float hrec[8][32 * 12];  // 12 KB: per group, per slot {h'[8], attr[4]}
    __shared__ float mid[8][256];       // 8 KB

    const int tid = threadIdx.x;
    const int nl = tid >> 5;
    const int u  = tid & 31;
    const int node = blockIdx.x * 8 + nl;
    const float inv_sqrt8 = 0.35355339059327373f;

    // fc2 fragment: f2r[j][q] = fcw2[j*128 + q*32 + u]
    float f2r[8][4];
    #pragma unroll
    for (int j = 0; j < 8; ++j) {
        f2r[j][0] = fcw2[j*128 + u];
        f2r[j][1] = fcw2[j*128 + 32 + u];
        f2r[j][2] = fcw2[j*128 + 64 + u];
        f2r[j][3] = fcw2[j*128 + 96 + u];
    }

    const int cnt = min(counts[node], CAP);
    int e0 = bucket[(long)node * CAP + u];
    const bool dummy = (u >= cnt);
    if (dummy) e0 = 0;
    int s0;

    // ---- prologue: lane u fills its slot's {h', attr} record ----
    if (EP) {
        const float4* ep = (const float4*)(epay + (long)e0 * 16);
        float4 p0 = ep[0], p1 = ep[1];
        const float4 p2 = ep[2], p3 = ep[3];
        s0 = dummy ? 0 : __float_as_int(p3.x);
        if (dummy) {   // h'=0 kills every term of a dummy slot
            p0 = make_float4(0.f, 0.f, 0.f, 0.f);
            p1 = make_float4(0.f, 0.f, 0.f, 0.f);
        }
        float* hr = hrec[nl] + u * 12;
        ((float4*)hr)[0] = p0;
        ((float4*)hr)[1] = p1;
        ((float4*)hr)[2] = p2;
        // no barrier: written and read by the same 32-lane group (wave-sync)
    } else {
        s0 = dummy ? 0 : eidx[e0];
        const float4 ea = ((const float4*)(ee + (long)e0 * 8))[0];
        const float4 eb = ((const float4*)(ee + (long)e0 * 8))[1];
        const float4 at = ((const float4*)eattr)[e0];
        const float eev[8] = {ea.x, ea.y, ea.z, ea.w, eb.x, eb.y, eb.z, eb.w};
        float* hr = hrec[nl] + u * 12;
        float h[8];
        #pragma unroll
        for (int j = 0; j < 8; ++j) {
            float pre = 0.f;
            #pragma unroll
            for (int b = 0; b < 8; ++b) pre += eev[b] * fcw1[b*8 + j];
            pre *= inv_sqrt8;
            const float s = pre / (1.f + __expf(-pre)) * inv_sqrt8;
            h[j] = dummy ? 0.f : s;
        }
        ((float4*)hr)[0] = make_float4(h[0], h[1], h[2], h[3]);
        ((float4*)hr)[1] = make_float4(h[4], h[5], h[6], h[7]);
        ((float4*)hr)[2] = at;
    }

    float msa = 0.f, msb = 0.f;
    float va0 = 0.f, va1 = 0.f, va2 = 0.f;
    float vb0 = 0.f, vb1 = 0.f, vb2 = 0.f;

    #define ACCUM(HA, HB, AT, Y)                                             \
    {                                                                        \
        const float es = __uint_as_float((Y).x << 16);                       \
        const float ex = __uint_as_float((Y).x & 0xffff0000u);               \
        const float ey = __uint_as_float((Y).y << 16);                       \
        const float ez = __uint_as_float((Y).y & 0xffff0000u);               \
        const float hh[8] = {HA.x,HA.y,HA.z,HA.w,HB.x,HB.y,HB.z,HB.w};       \
        float w00=0.f, w01=0.f, w10=0.f, w11=0.f;                            \
        _Pragma("unroll")                                                    \
        for (int j = 0; j < 8; ++j) {                                        \
            w00 += hh[j]*f2r[j][0]; w01 += hh[j]*f2r[j][1];                  \
            w10 += hh[j]*f2r[j][2]; w11 += hh[j]*f2r[j][3];                  \
        }                                                                    \
        const float a0 = AT.x, a1x = AT.y, a1y = AT.z, a1z = AT.w;           \
        msa += w00 * es * a0;                                                \
        msb += w11 * (ex*a1x + ey*a1y + ez*a1z);                             \
        const float t = w01 * es;                                            \
        va0 += t*a1x; va1 += t*a1y; va2 += t*a1z;                            \
        const float s = w10 * a0;                                            \
        vb0 += s*ex; vb1 += s*ey; vb2 += s*ez;                               \
    }

    #define GATHER(SLOT) \
        (*(const uint2*)(ysvh + (long)__shfl(s0, (SLOT), 32) * 128 + u * 4))

    // ---- main loop: 4 edges/iter, next 4 gathers in flight ----
    const int c0 = min(cnt, 32);
    {
        uint2 y0 = GATHER(0), y1 = GATHER(1), y2 = GATHER(2), y3 = GATHER(3);
        for (int k = 0; k < c0; k += 4) {
            const int kn = (k + 4) & 31;            // wrap: dummy-safe
            const uint2 n0 = GATHER(kn);
            const uint2 n1 = GATHER(kn + 1);
            const uint2 n2 = GATHER(kn + 2);
            const uint2 n3 = GATHER(kn + 3);
            const float4* h0p = (const float4*)(hrec[nl] + (k + 0) * 12);
            const float4* h1p = (const float4*)(hrec[nl] + (k + 1) * 12);
            const float4* h2p = (const float4*)(hrec[nl] + (k + 2) * 12);
            const float4* h3p = (const float4*)(hrec[nl] + (k + 3) * 12);
            const float4 A0 = h0p[0], B0 = h0p[1], T0 = h0p[2];
            const float4 A1 = h1p[0], B1 = h1p[1], T1 = h1p[2];
            const float4 A2 = h2p[0], B2 = h2p[1], T2 = h2p[2];
            const float4 A3 = h3p[0], B3 = h3p[1], T3 = h3p[2];
            ACCUM(A0, B0, T0, y0)
            ACCUM(A1, B1, T1, y1)
            ACCUM(A2, B2, T2, y2)
            ACCUM(A3, B3, T3, y3)
            y0 = n0; y1 = n1; y2 = n2; y3 = n3;
        }
    }

    // ---- rare tail (cnt > 32) ----
    if (cnt > 32) {
        int be = bucket[(long)node * CAP + 32 + u];
        if (32 + u >= cnt) be = 0;
        for (int k = 32; k < cnt; ++k) {
            const int e = __shfl(be, k - 32, 32);
            if (EP) {
                const float4* ep = (const float4*)(epay + (long)e * 16);
                const float4 HA = ep[0], HB = ep[1], at = ep[2];
                const int s = __float_as_int(ep[3].x);
                const uint2 y = *(const uint2*)(ysvh + (long)s * 128 + u * 4);
                ACCUM(HA, HB, at, y)
            } else {
                const int s = eidx[e];
                const float4 ea = ((const float4*)(ee + (long)e * 8))[0];
                const float4 eb = ((const float4*)(ee + (long)e * 8))[1];
                const float4 at = ((const float4*)eattr)[e];
                const float eev[8] = {ea.x, ea.y, ea.z, ea.w, eb.x, eb.y, eb.z, eb.w};
                float h[8];
                #pragma unroll
                for (int j = 0; j < 8; ++j) {
                    float pre = 0.f;
                    #pragma unroll
                    for (int b = 0; b < 8; ++b) pre += eev[b] * fcw1[b*8 + j];
                    pre *= inv_sqrt8;
                    h[j] = pre / (1.f + __expf(-pre)) * inv_sqrt8;
                }
                const float4 HA = make_float4(h[0], h[1], h[2], h[3]);
                const float4 HB = make_float4(h[4], h[5], h[6], h[7]);
                const uint2 y = *(const uint2*)(ysvh + (long)s * 128 + u * 4);
                ACCUM(HA, HB, at, y)
            }
        }
    }
    #undef GATHER
    #undef ACCUM

    msb *= 0.5773502691896258f;  // INV_SQRT3

    // ---- lin2 epilogue via mid-LDS transpose (intra-group, no barrier) ----
    float* m = mid[nl];
    m[u]       = msa;
    m[32 + u]  = msb;
    m[64  + u*3 + 0] = va0;  m[64  + u*3 + 1] = va1;  m[64  + u*3 + 2] = va2;
    m[160 + u*3 + 0] = vb0;  m[160 + u*3 + 1] = vb1;  m[160 + u*3 + 2] = vb2;

    float os = 0.f, ov0 = 0.f, ov1 = 0.f, ov2 = 0.f;
    #pragma unroll 8
    for (int q = 0; q < 32; ++q) {
        const float wsa = W2s[q*32 + u];
        const float wsb = W2s[(32 + q)*32 + u];
        os += m[q] * wsa + m[32 + q] * wsb;
        const float wva = W2v[q*32 + u];
        const float wvb = W2v[(32 + q)*32 + u];
        ov0 += m[64 + q*3 + 0] * wva + m[160 + q*3 + 0] * wvb;
        ov1 += m[64 + q*3 + 1] * wva + m[160 + q*3 + 1] * wvb;
        ov2 += m[64 + q*3 + 2] * wva + m[160 + q*3 + 2] * wvb;
    }

    const float sc = 0.03125f;  // (1/sqrt 16) * (1/sqrt 64)
    float* op = out + (long)node * 128;
    op[u]            += os  * sc;
    op[32 + 3*u + 0] += ov0 * sc;
    op[32 + 3*u + 1] += ov1 * sc;
    op[32 + 3*u + 2] += ov2 * sc;
}

extern "C" void kernel_launch(void* const* d_in, const int* in_sizes, int n_in,
                              void* d_out, int out_size, void* d_ws, size_t ws_size,
                              hipStream_t stream) {
    const float* x     = (const float*)d_in[0];
    const float* attr  = (const float*)d_in[1];
    const float* ee    = (const float*)d_in[2];
    const float* eattr = (const float*)d_in[3];
    const int*   eidx  = (const int*)  d_in[4];
    const float* W1s   = (const float*)d_in[5];
    const float* W1v   = (const float*)d_in[6];
    const float* fcw1  = (const float*)d_in[7];
    const float* fcw2  = (const float*)d_in[8];
    const float* W2s   = (const float*)d_in[9];
    const float* W2v   = (const float*)d_in[10];
    const float* Wscs  = (const float*)d_in[11];
    const float* Wscv  = (const float*)d_in[12];

    float* out = (float*)d_out;

    // workspace layout (16-B aligned)
    unsigned short* ysvh = (unsigned short*)d_ws;            // 50000*128 bf16 = 12.8 MB
    int*   counts = (int*)(ysvh + (long)N_NODES * 128);      // 50000 i32 = 0.2 MB
    int*   bucket = counts + N_NODES;                        // 50000*64 i32 = 12.8 MB
    float* epay   = (float*)(bucket + (long)N_NODES * CAP);  // 800000*64B = 51.2 MB

    const size_t need = (size_t)N_NODES*256 + (size_t)N_NODES*4
                      + (size_t)N_NODES*CAP*4 + (size_t)N_EDGES*64;   // 77.0 MB

    hipMemsetAsync(counts, 0, N_NODES * sizeof(int), stream);
    if (ws_size >= need) {
        prep_kernel<true><<<NODE_BLOCKS + BUCKET_BLOCKS, 256, 0, stream>>>(
            x, attr, W1s, W1v, Wscs, Wscv, ee, eattr, fcw1, eidx,
            counts, bucket, epay, ysvh, out);
        agg_kernel<true><<<N_NODES/8, 256, 0, stream>>>(ee, eattr, eidx, fcw1, fcw2,
            W2s, W2v, ysvh, counts, bucket, epay, out);
    } else {
        prep_kernel<false><<<NODE_BLOCKS + BUCKET_BLOCKS, 256, 0, stream>>>(
            x, attr, W1s, W1v, Wscs, Wscv, ee, eattr, fcw1, eidx,
            counts, bucket, epay, ysvh, out);
        agg_kernel<false><<<N_NODES/8, 256, 0, stream>>>(ee, eattr, eidx, fcw1, fcw2,
            W2s, W2v, ysvh, counts, bucket, epay, out);
    }
}